// Round 4
// baseline (956.017 us; speedup 1.0000x reference)
//
#include <hip/hip_runtime.h>
#include <math.h>

// Problem constants (reference: S,B,I,H = 1024,512,5,32; G=4H=128)
#define S_LEN 1024
#define BATCH 512
#define HID   32

__device__ __forceinline__ float fast_rcp(float x) { return __builtin_amdgcn_rcpf(x); }

__device__ __forceinline__ float sigmoid_f(float x) {
    return fast_rcp(1.0f + __expf(-x));
}

__device__ __forceinline__ float tanh_f(float x) {
    // overflow-safe: t = e^{-2|x|} in (0,1]; tanh = sign(x)*(1-t)/(1+t)
    float t = __expf(-2.0f * fabsf(x));
    float r = (1.0f - t) * fast_rcp(1.0f + t);
    return copysignf(r, x);
}

// broadcast lane k's float to all lanes through an SGPR (VALU only, no LDS)
__device__ __forceinline__ float rl(float v, int k) {
    return __int_as_float(__builtin_amdgcn_readlane(__float_as_int(v), k));
}

// Fused 3-layer LSTM + collapsed linear head, software-pipelined across waves.
// Block = 192 threads = 3 waves; wave w = layer w; blockIdx = batch element.
// At tick t, wave w processes step s = t - w; ONE __syncthreads per tick.
// Own-h stays in registers (distributed via v_readlane -> SGPR); only the
// layer->layer hand-off goes through a double-buffered LDS ring.
// Head: y = relu((w3 W2 W1) . h2 + (w3 W2 b1 + w3 b2 + b3)) -- the MLP is
// linear until the final relu, so wave 2 folds it into a dot-32 per step.
// Lane l owns gates l and l+64 of its layer (order i,f,g,o):
//   lanes 0-31 (j=l):     i_j (accA), g_j (accB)
//   lanes 32-63 (j=l-32): f_j (accA), o_j (accB)
__global__ __launch_bounds__(192, 2)
void lstm3_head(const float* __restrict__ x,
                const float* __restrict__ Wih0, const float* __restrict__ Whh0,
                const float* __restrict__ bih0, const float* __restrict__ bhh0,
                const float* __restrict__ Wih1, const float* __restrict__ Whh1,
                const float* __restrict__ bih1, const float* __restrict__ bhh1,
                const float* __restrict__ Wih2, const float* __restrict__ Whh2,
                const float* __restrict__ bih2, const float* __restrict__ bhh2,
                const float* __restrict__ w1, const float* __restrict__ b1,
                const float* __restrict__ w2, const float* __restrict__ b2,
                const float* __restrict__ w3, const float* __restrict__ b3,
                float* __restrict__ out)
{
    const int b = blockIdx.x;
    const int w = threadIdx.x >> 6;   // wave id == layer id, 0..2
    const int l = threadIdx.x & 63;
    const int j = l & 31;
    const bool lowHalf = (l < 32);
    const int gA = l;
    const int gB = l + 64;

    // ring[parity][producer layer 0|1][unit]
    __shared__ float ring[2][2][HID];
    for (int i = threadIdx.x; i < 2 * 2 * HID; i += 192)
        (&ring[0][0][0])[i] = 0.0f;

    const float* Wih = (w == 0) ? Wih0 : (w == 1) ? Wih1 : Wih2;
    const float* Whh = (w == 0) ? Whh0 : (w == 1) ? Whh1 : Whh2;
    const float* bih = (w == 0) ? bih0 : (w == 1) ? bih1 : bih2;
    const float* bhh = (w == 0) ? bhh0 : (w == 1) ? bhh1 : bhh2;

    float whhA[HID], whhB[HID];
#pragma unroll
    for (int k = 0; k < HID; ++k) {
        whhA[k] = Whh[gA * HID + k];
        whhB[k] = Whh[gB * HID + k];
    }
    float wihA[HID], wihB[HID];
    if (w == 0) {
#pragma unroll
        for (int k = 0; k < 5; ++k) {
            wihA[k] = Wih[gA * 5 + k];
            wihB[k] = Wih[gB * 5 + k];
        }
    } else {
#pragma unroll
        for (int k = 0; k < HID; ++k) {
            wihA[k] = Wih[gA * HID + k];
            wihB[k] = Wih[gB * HID + k];
        }
    }
    const float biasA = bih[gA] + bhh[gA];
    const float biasB = bih[gB] + bhh[gB];

    // ---- wave-2 prologue: collapse the linear MLP head ----
    // t_k = sum_i w3_i W2[i,k];  u_k = sum_i t_i W1[i,k];
    // beta = sum_i t_i b1_i + sum_i w3_i b2_i + b3
    float u_own = 0.0f, beta = 0.0f;
    if (w == 2) {
        float t_own = 0.0f;
#pragma unroll
        for (int k = 0; k < HID; ++k)
            t_own += w3[k] * w2[k * HID + j];
        float uo = 0.0f, bt = 0.0f;
#pragma unroll
        for (int k = 0; k < HID; ++k) {
            float tk = rl(t_own, k);       // t_k lives in lane k
            uo += tk * w1[k * HID + j];
            bt += tk * b1[k] + w3[k] * b2[k];
        }
        u_own = uo;
        beta = bt + b3[0];
    }

    float c = 0.0f;
    float h = 0.0f;   // h_{l&31} of this layer (redundant in both halves)

    const float* xb = x + (size_t)b * 5;
    float xv0 = 0.f, xv1 = 0.f, xv2 = 0.f, xv3 = 0.f, xv4 = 0.f;
    if (w == 0) { xv0 = xb[0]; xv1 = xb[1]; xv2 = xb[2]; xv3 = xb[3]; xv4 = xb[4]; }

    __syncthreads();  // ring zero-init visible

    for (int t = 0; t < S_LEN + 2; ++t) {
        const int s = t - w;
        const bool active = ((unsigned)s < S_LEN);
        const int p = t & 1;

        // ---- cross-layer input: batched LDS loads issued first (latency
        //      hides under the Whh/readlane work below) ----
        float4 hin[HID / 4];
        if (w > 0) {
            const float4* r4 = reinterpret_cast<const float4*>(&ring[p][w - 1][0]);
#pragma unroll
            for (int k4 = 0; k4 < HID / 4; ++k4) hin[k4] = r4[k4];
        }

        // ---- Whh . h_own : h distributed lane->SGPR via readlane ----
        float aA0 = biasA, aA1 = 0.f, aA2 = 0.f, aA3 = 0.f;
        float aB0 = biasB, aB1 = 0.f, aB2 = 0.f, aB3 = 0.f;
#pragma unroll
        for (int k = 0; k < HID; k += 4) {
            float h0 = rl(h, k + 0);
            float h1 = rl(h, k + 1);
            float h2 = rl(h, k + 2);
            float h3 = rl(h, k + 3);
            aA0 += whhA[k + 0] * h0;  aB0 += whhB[k + 0] * h0;
            aA1 += whhA[k + 1] * h1;  aB1 += whhB[k + 1] * h1;
            aA2 += whhA[k + 2] * h2;  aB2 += whhB[k + 2] * h2;
            aA3 += whhA[k + 3] * h3;  aB3 += whhB[k + 3] * h3;
        }

        if (w == 0) {
            aA0 += wihA[0] * xv0;  aB0 += wihB[0] * xv0;
            aA1 += wihA[1] * xv1;  aB1 += wihB[1] * xv1;
            aA2 += wihA[2] * xv2;  aB2 += wihB[2] * xv2;
            aA3 += wihA[3] * xv3;  aB3 += wihB[3] * xv3;
            aA0 += wihA[4] * xv4;  aB0 += wihB[4] * xv4;
            if (s + 1 < S_LEN) {
                const float* xn = xb + (size_t)(s + 1) * BATCH * 5;
                xv0 = xn[0]; xv1 = xn[1]; xv2 = xn[2]; xv3 = xn[3]; xv4 = xn[4];
            }
        } else {
#pragma unroll
            for (int k4 = 0; k4 < HID / 4; ++k4) {
                float4 hv = hin[k4];
                aA0 += wihA[4 * k4 + 0] * hv.x;  aB0 += wihB[4 * k4 + 0] * hv.x;
                aA1 += wihA[4 * k4 + 1] * hv.y;  aB1 += wihB[4 * k4 + 1] * hv.y;
                aA2 += wihA[4 * k4 + 2] * hv.z;  aB2 += wihB[4 * k4 + 2] * hv.z;
                aA3 += wihA[4 * k4 + 3] * hv.w;  aB3 += wihB[4 * k4 + 3] * hv.w;
            }
        }
        float accA = (aA0 + aA1) + (aA2 + aA3);
        float accB = (aB0 + aB1) + (aB2 + aB3);

        // ---- exchange halves: both halves get all 4 gates of unit j ----
        float pA = __shfl_xor(accA, 32);
        float pB = __shfl_xor(accB, 32);
        float gi = lowHalf ? accA : pA;
        float gf = lowHalf ? pA : accA;
        float gg = lowHalf ? accB : pB;
        float go = lowHalf ? pB : accB;

        gi = sigmoid_f(gi);
        gf = sigmoid_f(gf);
        gg = tanh_f(gg);
        go = sigmoid_f(go);
        float c_new = gf * c + gi * gg;
        float h_new = go * tanh_f(c_new);   // redundant in both halves

        if (active) {
            c = c_new;
            h = h_new;
            if (w < 2) {
                if (lowHalf) ring[p ^ 1][w][j] = h_new;   // next tick's input for wave w+1
            } else {
                // fused head: y[s,b] = relu(u . h + beta), butterfly over 32 units
                float prt = u_own * h_new;
                prt += __shfl_xor(prt, 1);
                prt += __shfl_xor(prt, 2);
                prt += __shfl_xor(prt, 4);
                prt += __shfl_xor(prt, 8);
                prt += __shfl_xor(prt, 16);
                if (l == 0) out[(size_t)s * BATCH + b] = fmaxf(prt + beta, 0.0f);
            }
        }
        __syncthreads();  // tick boundary
    }
}

extern "C" void kernel_launch(void* const* d_in, const int* in_sizes, int n_in,
                              void* d_out, int out_size, void* d_ws, size_t ws_size,
                              hipStream_t stream)
{
    const float* x    = (const float*)d_in[0];
    const float* Wih0 = (const float*)d_in[1];
    const float* Whh0 = (const float*)d_in[2];
    const float* bih0 = (const float*)d_in[3];
    const float* bhh0 = (const float*)d_in[4];
    const float* Wih1 = (const float*)d_in[5];
    const float* Whh1 = (const float*)d_in[6];
    const float* bih1 = (const float*)d_in[7];
    const float* bhh1 = (const float*)d_in[8];
    const float* Wih2 = (const float*)d_in[9];
    const float* Whh2 = (const float*)d_in[10];
    const float* bih2 = (const float*)d_in[11];
    const float* bhh2 = (const float*)d_in[12];
    const float* w1   = (const float*)d_in[13];
    const float* b1   = (const float*)d_in[14];
    const float* w2   = (const float*)d_in[15];
    const float* b2   = (const float*)d_in[16];
    const float* w3   = (const float*)d_in[17];
    const float* b3   = (const float*)d_in[18];

    lstm3_head<<<BATCH, 192, 0, stream>>>(x, Wih0, Whh0, bih0, bhh0,
                                          Wih1, Whh1, bih1, bhh1,
                                          Wih2, Whh2, bih2, bhh2,
                                          w1, b1, w2, b2, w3, b3,
                                          (float*)d_out);
}